// Round 18
// baseline (129.097 us; speedup 1.0000x reference)
//
#include <hip/hip_runtime.h>
#include <math.h>

#define C_DIM 256
#define HH 32
#define WW 32
#define ZZ 8
#define HD 32

typedef __attribute__((ext_vector_type(8))) short bf16x8;
typedef __attribute__((ext_vector_type(4))) float f32x4;
typedef __attribute__((ext_vector_type(4))) unsigned int u32x4;

__device__ inline unsigned short f2bf(float f) {
    unsigned int u = __builtin_bit_cast(unsigned int, f);
    u += 0x7FFF + ((u >> 16) & 1);
    return (unsigned short)(u >> 16);
}
__device__ inline float bf2f(unsigned short h) {
    unsigned int u = ((unsigned int)h) << 16;
    return __builtin_bit_cast(float, u);
}
__device__ inline unsigned int cvtpk_bf16(float a, float b) {
    unsigned int r;
    asm("v_cvt_pk_bf16_f32 %0, %1, %2" : "=v"(r) : "v"(a), "v"(b));
    return r;  // lo = bf16(a), hi = bf16(b)
}

// softmax scale with log2(e) folded in: exp2(q*k*QSCALE) == exp(q*k/sqrt(32))
#define QSCALE (0.17677669529663689f * 1.4426950408889634f)

// ---------------------------------------------------------------------------
// Split-bf16 MFMA GEMM with split-K, double-buffered LDS + reg prefetch.
// C[i,j] = sum_k A[i,k]*B[j,k] (+bias[j] if gridDim.z==1 && bias)
// Epilogue modes:
//   qb_out != null : write f2bf(val*QSCALE) to qb_out[row*N+col]; skip C.
//   kb_out != null : write C as usual; ALSO if col<128 write tiled bf16 K:
//                    kb_out[((h*KTp+kt)*128+mi)*32+c].
// ---------------------------------------------------------------------------
__global__ __launch_bounds__(256) void gemm_split_kernel(
    const float* __restrict__ A, const float* __restrict__ B,
    const float* __restrict__ bias, float* __restrict__ C,
    int M, int N, int K,
    unsigned short* __restrict__ qb_out,
    unsigned short* __restrict__ kb_out, int KTp) {
    __shared__ unsigned short Ah[2][2560], Al[2][2560], Bh[2][2560], Bl[2][2560];
    int t = threadIdx.x;
    int wave = t >> 6, lane = t & 63;
    int lg = lane >> 4, lc = lane & 15;
    int wm = wave >> 1, wn = wave & 1;
    int m0 = blockIdx.y * 64, n0 = blockIdx.x * 64;
    int Kc = K / gridDim.z;
    int kbeg = blockIdx.z * Kc;
    float* Cz = C + (long)blockIdx.z * M * N;
    int srow = t >> 2, sc8 = (t & 3) * 8;
    const float* aBase = A + (long)(m0 + srow) * K + kbeg + sc8;
    const float* bBase = B + (long)(n0 + srow) * K + kbeg + sc8;
    int nIter = Kc / 32;

    f32x4 acc[2][2];
#pragma unroll
    for (int i = 0; i < 2; ++i)
#pragma unroll
        for (int j = 0; j < 2; ++j) acc[i][j] = (f32x4){0.f, 0.f, 0.f, 0.f};

    auto cvt_store = [&](int buf, f32x4 a0, f32x4 a1, f32x4 b0, f32x4 b1) {
        bf16x8 h, l;
#pragma unroll
        for (int j = 0; j < 8; ++j) {
            float v = (j < 4) ? a0[j] : a1[j - 4];
            unsigned short hu = f2bf(v);
            h[j] = (short)hu;
            l[j] = (short)f2bf(v - bf2f(hu));
        }
        *reinterpret_cast<bf16x8*>(&Ah[buf][srow * 40 + sc8]) = h;
        *reinterpret_cast<bf16x8*>(&Al[buf][srow * 40 + sc8]) = l;
#pragma unroll
        for (int j = 0; j < 8; ++j) {
            float v = (j < 4) ? b0[j] : b1[j - 4];
            unsigned short hu = f2bf(v);
            h[j] = (short)hu;
            l[j] = (short)f2bf(v - bf2f(hu));
        }
        *reinterpret_cast<bf16x8*>(&Bh[buf][srow * 40 + sc8]) = h;
        *reinterpret_cast<bf16x8*>(&Bl[buf][srow * 40 + sc8]) = l;
    };

    {
        f32x4 a0 = *reinterpret_cast<const f32x4*>(aBase);
        f32x4 a1 = *reinterpret_cast<const f32x4*>(aBase + 4);
        f32x4 b0 = *reinterpret_cast<const f32x4*>(bBase);
        f32x4 b1 = *reinterpret_cast<const f32x4*>(bBase + 4);
        cvt_store(0, a0, a1, b0, b1);
    }
    __syncthreads();

    for (int k = 0; k < nIter; ++k) {
        int cur = k & 1;
        bool more = (k + 1 < nIter);
        f32x4 na0, na1, nb0, nb1;
        if (more) {
            const float* ap = aBase + (k + 1) * 32;
            const float* bp = bBase + (k + 1) * 32;
            na0 = *reinterpret_cast<const f32x4*>(ap);
            na1 = *reinterpret_cast<const f32x4*>(ap + 4);
            nb0 = *reinterpret_cast<const f32x4*>(bp);
            nb1 = *reinterpret_cast<const f32x4*>(bp + 4);
        }
        bf16x8 afh[2], afl[2], bfh[2], bfl[2];
#pragma unroll
        for (int i = 0; i < 2; ++i) {
            int ar = wm * 32 + i * 16 + lc;
            afh[i] = *reinterpret_cast<const bf16x8*>(&Ah[cur][ar * 40 + lg * 8]);
            afl[i] = *reinterpret_cast<const bf16x8*>(&Al[cur][ar * 40 + lg * 8]);
            int br = wn * 32 + i * 16 + lc;
            bfh[i] = *reinterpret_cast<const bf16x8*>(&Bh[cur][br * 40 + lg * 8]);
            bfl[i] = *reinterpret_cast<const bf16x8*>(&Bl[cur][br * 40 + lg * 8]);
        }
#pragma unroll
        for (int i = 0; i < 2; ++i)
#pragma unroll
            for (int j = 0; j < 2; ++j) {
                acc[i][j] = __builtin_amdgcn_mfma_f32_16x16x32_bf16(afh[i], bfh[j], acc[i][j], 0, 0, 0);
                acc[i][j] = __builtin_amdgcn_mfma_f32_16x16x32_bf16(afh[i], bfl[j], acc[i][j], 0, 0, 0);
                acc[i][j] = __builtin_amdgcn_mfma_f32_16x16x32_bf16(afl[i], bfh[j], acc[i][j], 0, 0, 0);
            }
        if (more) {
            cvt_store(cur ^ 1, na0, na1, nb0, nb1);
            __syncthreads();
        }
    }
#pragma unroll
    for (int i = 0; i < 2; ++i)
#pragma unroll
        for (int j = 0; j < 2; ++j)
#pragma unroll
            for (int r = 0; r < 4; ++r) {
                int row = m0 + wm * 32 + i * 16 + lg * 4 + r;
                int col = n0 + wn * 32 + j * 16 + lc;
                float bv = bias ? bias[col] : 0.f;
                float val = acc[i][j][r] + bv;
                if (qb_out) {
                    qb_out[(long)row * N + col] = f2bf(val * QSCALE);
                } else {
                    Cz[(long)row * N + col] = val;
                    if (kb_out && col < 128) {
                        int h = col >> 5, c = col & 31, kt = row >> 7, mi = row & 127;
                        kb_out[((long)(h * KTp + kt) * 128 + mi) * 32 + c] = f2bf(val);
                    }
                }
            }
}

// ---------------------------------------------------------------------------
// Fused: sum KS split-K planes + bias, then LayerNorm + exact GELU.
// ---------------------------------------------------------------------------
__global__ void reduce_ln_gelu_kernel(const float* __restrict__ part,
                                      const float* __restrict__ bias,
                                      const float* __restrict__ g,
                                      const float* __restrict__ bb,
                                      float* __restrict__ xr, int MN, int KS) {
    int m = blockIdx.x;
    int c = threadIdx.x;
    float v = bias[c];
    for (int z = 0; z < KS; ++z) v += part[(long)z * MN + m * C_DIM + c];
    __shared__ float wred[4];
    float s = v;
    for (int off = 32; off; off >>= 1) s += __shfl_down(s, off);
    if ((c & 63) == 0) wred[c >> 6] = s;
    __syncthreads();
    float mean = (wred[0] + wred[1] + wred[2] + wred[3]) * (1.f / 256.f);
    __syncthreads();
    float d = v - mean;
    float s2 = d * d;
    for (int off = 32; off; off >>= 1) s2 += __shfl_down(s2, off);
    if ((c & 63) == 0) wred[c >> 6] = s2;
    __syncthreads();
    float var = (wred[0] + wred[1] + wred[2] + wred[3]) * (1.f / 256.f);
    float y = d * rsqrtf(var + 1e-5f) * g[c] + bb[c];
    float ge = 0.5f * y * (1.f + erff(y * 0.70710678118654752f));
    xr[m * C_DIM + c] = ge;
}

// ---------------------------------------------------------------------------
// im2col for SR conv.
// ---------------------------------------------------------------------------
template <int S>
__global__ void im2col_kernel(const float* __restrict__ x, float* __restrict__ im, int Ws) {
    constexpr int T = S * S;
    __shared__ float patch[T * 257];
    int m = blockIdx.x;
    int z = m % ZZ;
    int wo = (m / ZZ) % Ws;
    int ho = m / (ZZ * Ws);
    int t = threadIdx.x;
#pragma unroll
    for (int tap = 0; tap < T; ++tap) {
        int kh = tap / S, kw = tap % S;
        int row = (ho * S + kh) * (WW * ZZ) + (wo * S + kw) * ZZ + z;
        patch[tap * 257 + t] = x[row * C_DIM + t];
    }
    __syncthreads();
#pragma unroll
    for (int rep = 0; rep < T; ++rep) {
        int k = rep * 256 + t;
        int ci = k / T, tap = k % T;
        im[(long)m * (256 * T) + k] = patch[tap * 257 + ci];
    }
}

// ---------------------------------------------------------------------------
// LayerNorm + exact GELU (fallback path when split-K not used)
// ---------------------------------------------------------------------------
__global__ void ln_gelu_kernel(float* __restrict__ xr, const float* __restrict__ g,
                               const float* __restrict__ bb) {
    int m = blockIdx.x;
    int c = threadIdx.x;
    float v = xr[m * C_DIM + c];
    __shared__ float wred[4];
    float s = v;
    for (int off = 32; off; off >>= 1) s += __shfl_down(s, off);
    if ((c & 63) == 0) wred[c >> 6] = s;
    __syncthreads();
    float mean = (wred[0] + wred[1] + wred[2] + wred[3]) * (1.f / 256.f);
    __syncthreads();
    float d = v - mean;
    float s2 = d * d;
    for (int off = 32; off; off >>= 1) s2 += __shfl_down(s2, off);
    if ((c & 63) == 0) wred[c >> 6] = s2;
    __syncthreads();
    float var = (wred[0] + wred[1] + wred[2] + wred[3]) * (1.f / 256.f);
    float y = d * rsqrtf(var + 1e-5f) * g[c] + bb[c];
    float ge = 0.5f * y * (1.f + erff(y * 0.70710678118654752f));
    xr[m * C_DIM + c] = ge;
}

// ---------------------------------------------------------------------------
// Depthwise 3x3x1 conv on V + residual; writes tiled V^T bf16:
// vt[((hh*KT+kt)*32 + d)*128 + s], where slot s holds key mi per the
// in-register P order of the swapped-QK attention:
//   mi = a<<5 | u<<4 | g<<2 | v  ->  s = a<<5 | g<<3 | u<<2 | v
// (a=mi>>5 2b, u=(mi>>4)&1, g=(mi>>2)&3, v=mi&3; bijective).
// ---------------------------------------------------------------------------
__global__ void dw_conv_kernel(const float* __restrict__ kv, const float* __restrict__ lw,
                               const float* __restrict__ lb, unsigned short* __restrict__ vt,
                               int Ws, int Hs, int KT) {
    int m = blockIdx.x;
    int ch = threadIdx.x;
    int z = m % ZZ;
    int wo = (m / ZZ) % Ws;
    int ho = m / (ZZ * Ws);
    float acc = lb[ch];
#pragma unroll
    for (int kh = 0; kh < 3; ++kh) {
        int h = ho + kh - 1;
        if (h < 0 || h >= Hs) continue;
#pragma unroll
        for (int kw = 0; kw < 3; ++kw) {
            int w2 = wo + kw - 1;
            if (w2 < 0 || w2 >= Ws) continue;
            int mm = (h * Ws + w2) * ZZ + z;
            acc += kv[mm * C_DIM + 128 + ch] * lw[ch * 9 + kh * 3 + kw];
        }
    }
    int hh = ch >> 5, d = ch & 31, kt = m >> 7, mi = m & 127;
    int a = mi >> 5, u = (mi >> 4) & 1, g = (mi >> 2) & 3, v = mi & 3;
    int s = (a << 5) | (g << 3) | (u << 2) | v;
    vt[((long)(hh * KT + kt) * 32 + d) * 128 + s] = f2bf(kv[m * C_DIM + 128 + ch] + acc);
}

// ---------------------------------------------------------------------------
// Fused MFMA flash attention, both branches, NO-MAX softmax, SWAPPED-QK,
// FULLY IN-REGISTER SOFTMAX (zero LDS), TWO Q-GROUPS PER WAVE,
// DOUBLE-BUFFERED K *AND* V prefetch (r18): V for tile kt+1 is issued right
// after this tile's QK (alongside the K prefetch), so the 8 serialized V
// loads get a full tile of slack instead of stalling PV (~1000cy tail in
// r17, where V was loaded and consumed within the same tile).
// Grid (64, 8), 256 threads = 4 waves; wave w owns 32 q-rows as two 16-row
// groups qf0/qf1 SHARING the K/V fragment loads.
// kb tiled: [h][kt][128 keys][32 d]; vt slot-permuted [h][kt][32 d][128 pos].
// ---------------------------------------------------------------------------
__global__ __launch_bounds__(256, 2) void attn_fused_kernel(
    const unsigned short* __restrict__ qb,
    const unsigned short* __restrict__ kb1, const unsigned short* __restrict__ vt1,
    const unsigned short* __restrict__ kb2, const unsigned short* __restrict__ vt2,
    float* __restrict__ outcat) {
    int wave = threadIdx.x >> 6;
    int lane = threadIdx.x & 63;
    int lg = lane >> 4;
    int lc = lane & 15;
    int by = blockIdx.y;
    int big = ((by >> 2) == 0);  // by 0..3 = branch-2 (M=2048), dispatched first
    int head = by & 3;
    const unsigned short* kb = big ? kb2 : kb1;
    const unsigned short* vt = big ? vt2 : vt1;
    int KT = big ? 16 : 4;
    int col_base = big ? 128 : 0;
    int q0 = blockIdx.x * 128 + wave * 32;

    bf16x8 qf0 = *reinterpret_cast<const bf16x8*>(qb + (long)(q0 + lc) * C_DIM + col_base + head * HD + lg * 8);
    bf16x8 qf1 = *reinterpret_cast<const bf16x8*>(qb + (long)(q0 + 16 + lc) * C_DIM + col_base + head * HD + lg * 8);

    const unsigned short* kbase = kb + (long)head * KT * 4096;
    const unsigned short* vbase = vt + (long)head * KT * 4096;

    f32x4 o00 = {0.f, 0.f, 0.f, 0.f}, o01 = {0.f, 0.f, 0.f, 0.f};
    f32x4 o10 = {0.f, 0.f, 0.f, 0.f}, o11 = {0.f, 0.f, 0.f, 0.f};
    float lsum0 = 0.f, lsum1 = 0.f;

    bf16x8 kf[8];
    bf16x8 vf0c[4], vf1c[4];
#pragma unroll
    for (int c = 0; c < 8; ++c)
        kf[c] = *reinterpret_cast<const bf16x8*>(kbase + (16 * c + lc) * 32 + lg * 8);
#pragma unroll
    for (int c2 = 0; c2 < 4; ++c2) {
        vf0c[c2] = *reinterpret_cast<const bf16x8*>(vbase + lc * 128 + c2 * 32 + lg * 8);
        vf1c[c2] = *reinterpret_cast<const bf16x8*>(vbase + (16 + lc) * 128 + c2 * 32 + lg * 8);
    }

    for (int kt = 0; kt < KT; ++kt) {
        // QK^T swapped, both q-groups share kf: s*[c][r] = S[key=16c+4lg+r][query=lc]
        f32x4 s0[8], s1[8];
        f32x4 z = {0.f, 0.f, 0.f, 0.f};
#pragma unroll
        for (int c = 0; c < 8; ++c) {
            s0[c] = __builtin_amdgcn_mfma_f32_16x16x32_bf16(kf[c], qf0, z, 0, 0, 0);
            s1[c] = __builtin_amdgcn_mfma_f32_16x16x32_bf16(kf[c], qf1, z, 0, 0, 0);
        }
        // prefetch next tile's K (overwrite, consumed) AND V (separate bufs)
        bf16x8 vf0n[4], vf1n[4];
        if (kt + 1 < KT) {
            const unsigned short* knext = kbase + (long)(kt + 1) * 4096;
            const unsigned short* vnext = vbase + (long)(kt + 1) * 4096;
#pragma unroll
            for (int c = 0; c < 8; ++c)
                kf[c] = *reinterpret_cast<const bf16x8*>(knext + (16 * c + lc) * 32 + lg * 8);
#pragma unroll
            for (int c2 = 0; c2 < 4; ++c2) {
                vf0n[c2] = *reinterpret_cast<const bf16x8*>(vnext + lc * 128 + c2 * 32 + lg * 8);
                vf1n[c2] = *reinterpret_cast<const bf16x8*>(vnext + (16 + lc) * 128 + c2 * 32 + lg * 8);
            }
        }
        // in-register softmax + PV A-frag packing, group 0 then group 1
#pragma unroll
        for (int c2 = 0; c2 < 4; ++c2) {
            unsigned int w0, w1, w2, w3;
            {
                int c = 2 * c2;
                float p0 = __builtin_amdgcn_exp2f(s0[c][0]);
                float p1 = __builtin_amdgcn_exp2f(s0[c][1]);
                float p2 = __builtin_amdgcn_exp2f(s0[c][2]);
                float p3 = __builtin_amdgcn_exp2f(s0[c][3]);
                lsum0 += (p0 + p1) + (p2 + p3);
                w0 = cvtpk_bf16(p0, p1);
                w1 = cvtpk_bf16(p2, p3);
            }
            {
                int c = 2 * c2 + 1;
                float p0 = __builtin_amdgcn_exp2f(s0[c][0]);
                float p1 = __builtin_amdgcn_exp2f(s0[c][1]);
                float p2 = __builtin_amdgcn_exp2f(s0[c][2]);
                float p3 = __builtin_amdgcn_exp2f(s0[c][3]);
                lsum0 += (p0 + p1) + (p2 + p3);
                w2 = cvtpk_bf16(p0, p1);
                w3 = cvtpk_bf16(p2, p3);
            }
            u32x4 pw = {w0, w1, w2, w3};
            bf16x8 pa = __builtin_bit_cast(bf16x8, pw);
            o00 = __builtin_amdgcn_mfma_f32_16x16x32_bf16(pa, vf0c[c2], o00, 0, 0, 0);
            o01 = __builtin_amdgcn_mfma_f32_16x16x32_bf16(pa, vf1c[c2], o01, 0, 0, 0);
        }
#pragma unroll
        for (int c2 = 0; c2 < 4; ++c2) {
            unsigned int w0, w1, w2, w3;
            {
                int c = 2 * c2;
                float p0 = __builtin_amdgcn_exp2f(s1[c][0]);
                float p1 = __builtin_amdgcn_exp2f(s1[c][1]);
                float p2 = __builtin_amdgcn_exp2f(s1[c][2]);
                float p3 = __builtin_amdgcn_exp2f(s1[c][3]);
                lsum1 += (p0 + p1) + (p2 + p3);
                w0 = cvtpk_bf16(p0, p1);
                w1 = cvtpk_bf16(p2, p3);
            }
            {
                int c = 2 * c2 + 1;
                float p0 = __builtin_amdgcn_exp2f(s1[c][0]);
                float p1 = __builtin_amdgcn_exp2f(s1[c][1]);
                float p2 = __builtin_amdgcn_exp2f(s1[c][2]);
                float p3 = __builtin_amdgcn_exp2f(s1[c][3]);
                lsum1 += (p0 + p1) + (p2 + p3);
                w2 = cvtpk_bf16(p0, p1);
                w3 = cvtpk_bf16(p2, p3);
            }
            u32x4 pw = {w0, w1, w2, w3};
            bf16x8 pa = __builtin_bit_cast(bf16x8, pw);
            o10 = __builtin_amdgcn_mfma_f32_16x16x32_bf16(pa, vf0c[c2], o10, 0, 0, 0);
            o11 = __builtin_amdgcn_mfma_f32_16x16x32_bf16(pa, vf1c[c2], o11, 0, 0, 0);
        }
        if (kt + 1 < KT) {
#pragma unroll
            for (int c2 = 0; c2 < 4; ++c2) {
                vf0c[c2] = vf0n[c2];
                vf1c[c2] = vf1n[c2];
            }
        }
    }
    // reduce each group's lsum across the 4 lg-groups, then distribute
    lsum0 += __shfl_xor(lsum0, 16);
    lsum0 += __shfl_xor(lsum0, 32);
    lsum1 += __shfl_xor(lsum1, 16);
    lsum1 += __shfl_xor(lsum1, 32);
#pragma unroll
    for (int r = 0; r < 4; ++r) {
        float ls = __shfl(lsum0, lg * 4 + r);
        float inv = 1.f / ls;
        int row = q0 + lg * 4 + r;
        outcat[(long)row * C_DIM + col_base + head * HD + lc] = o00[r] * inv;
        outcat[(long)row * C_DIM + col_base + head * HD + 16 + lc] = o01[r] * inv;
    }
#pragma unroll
    for (int r = 0; r < 4; ++r) {
        float ls = __shfl(lsum1, lg * 4 + r);
        float inv = 1.f / ls;
        int row = q0 + 16 + lg * 4 + r;
        outcat[(long)row * C_DIM + col_base + head * HD + lc] = o10[r] * inv;
        outcat[(long)row * C_DIM + col_base + head * HD + 16 + lc] = o11[r] * inv;
    }
}

// ---------------------------------------------------------------------------
extern "C" void kernel_launch(void* const* d_in, const int* in_sizes, int n_in,
                              void* d_out, int out_size, void* d_ws, size_t ws_size,
                              hipStream_t stream) {
    const float* x      = (const float*)d_in[0];
    const float* Wq     = (const float*)d_in[1];
    const float* sr1_w  = (const float*)d_in[2];
    const float* sr1_b  = (const float*)d_in[3];
    const float* ln1_w  = (const float*)d_in[4];
    const float* ln1_b  = (const float*)d_in[5];
    const float* sr2_w  = (const float*)d_in[6];
    const float* sr2_b  = (const float*)d_in[7];
    const float* ln2_w  = (const float*)d_in[8];
    const float* ln2_b  = (const float*)d_in[9];
    const float* Wkv1   = (const float*)d_in[10];
    const float* Wkv2   = (const float*)d_in[11];
    const float* lc1_w  = (const float*)d_in[12];
    const float* lc1_b  = (const float*)d_in[13];
    const float* lc2_w  = (const float*)d_in[14];
    const float* lc2_b  = (const float*)d_in[15];
    const float* proj_w = (const float*)d_in[16];
    const float* proj_b = (const float*)d_in[17];
    float* out = (float*)d_out;
    char* wsb = (char*)d_ws;

    float* buf0 = (float*)wsb;                                  // sr1 partials -> cat (8 MB)
    unsigned short* qb = (unsigned short*)(wsb + 8388608);      // 4 MB
    float* im = (float*)(wsb + 12582912);                       // 8 MB
    float* xr1 = (float*)(wsb + 20971520);
    float* kv1 = (float*)(wsb + 21495808);
    unsigned short* kb1 = (unsigned short*)(wsb + 22020096);
    unsigned short* vt1 = (unsigned short*)(wsb + 22151168);
    float* xr2 = (float*)(wsb + 22282240);
    float* kv2 = (float*)(wsb + 24379392);
    unsigned short* kb2 = (unsigned short*)(wsb + 26476544);
    unsigned short* vt2 = (unsigned short*)(wsb + 27000832);
    float* part2 = (float*)(wsb + 27525120);

    float* cat = buf0;
    float* part1 = buf0;

    int KS2 = 1;
    if (ws_size >= 27525120ull + 4ull * 2048 * 256 * 4) KS2 = 4;
    else if (ws_size >= 27525120ull + 2ull * 2048 * 256 * 4) KS2 = 2;

    // q = bf16(scale * x @ Wq.T), fused epilogue
    gemm_split_kernel<<<dim3(4, 128, 1), 256, 0, stream>>>(x, Wq, nullptr, (float*)qb, 8192, 256, 256,
                                                           qb, nullptr, 0);

    // ---- branch 1 (stride 4): M = 512, K = 4096, split-K 16 ----
    im2col_kernel<4><<<512, 256, 0, stream>>>(x, im, 8);
    gemm_split_kernel<<<dim3(4, 8, 16), 256, 0, stream>>>(im, sr1_w, nullptr, part1, 512, 256, 4096,
                                                          nullptr, nullptr, 0);
    reduce_ln_gelu_kernel<<<512, 256, 0, stream>>>(part1, sr1_b, ln1_w, ln1_b, xr1, 512 * 256, 16);
    gemm_split_kernel<<<dim3(4, 8, 1), 256, 0, stream>>>(xr1, Wkv1, nullptr, kv1, 512, 256, 256,
                                                         nullptr, kb1, 4);
    dw_conv_kernel<<<512, 128, 0, stream>>>(kv1, lc1_w, lc1_b, vt1, 8, 8, 4);

    // ---- branch 2 (stride 2): M = 2048, K = 1024, split-K KS2 ----
    im2col_kernel<2><<<2048, 256, 0, stream>>>(x, im, 16);
    if (KS2 > 1) {
        gemm_split_kernel<<<dim3(4, 32, KS2), 256, 0, stream>>>(im, sr2_w, nullptr, part2, 2048, 256, 1024,
                                                                nullptr, nullptr, 0);
        reduce_ln_gelu_kernel<<<2048, 256, 0, stream>>>(part2, sr2_b, ln2_w, ln2_b, xr2, 2048 * 256, KS2);
    } else {
        gemm_split_kernel<<<dim3(4, 32, 1), 256, 0, stream>>>(im, sr2_w, sr2_b, xr2, 2048, 256, 1024,
                                                              nullptr, nullptr, 0);
        ln_gelu_kernel<<<2048, 256, 0, stream>>>(xr2, ln2_w, ln2_b);
    }
    gemm_split_kernel<<<dim3(4, 32, 1), 256, 0, stream>>>(xr2, Wkv2, nullptr, kv2, 2048, 256, 256,
                                                          nullptr, kb2, 16);
    dw_conv_kernel<<<2048, 128, 0, stream>>>(kv2, lc2_w, lc2_b, vt2, 16, 16, 16);

    // fused attention over both branches (4 waves / 128 q-rows per block)
    attn_fused_kernel<<<dim3(64, 8), 256, 0, stream>>>(qb, kb1, vt1, kb2, vt2, cat);

    // out = cat @ proj_w.T + proj_b
    gemm_split_kernel<<<dim3(4, 128, 1), 256, 0, stream>>>(cat, proj_w, proj_b, out, 8192, 256, 256,
                                                           nullptr, nullptr, 0);
}

// Round 19
// 122.027 us; speedup vs baseline: 1.0579x; 1.0579x over previous
//
#include <hip/hip_runtime.h>
#include <math.h>

#define C_DIM 256
#define HH 32
#define WW 32
#define ZZ 8
#define HD 32

typedef __attribute__((ext_vector_type(8))) short bf16x8;
typedef __attribute__((ext_vector_type(4))) float f32x4;
typedef __attribute__((ext_vector_type(4))) unsigned int u32x4;

__device__ inline unsigned short f2bf(float f) {
    unsigned int u = __builtin_bit_cast(unsigned int, f);
    u += 0x7FFF + ((u >> 16) & 1);
    return (unsigned short)(u >> 16);
}
__device__ inline float bf2f(unsigned short h) {
    unsigned int u = ((unsigned int)h) << 16;
    return __builtin_bit_cast(float, u);
}
__device__ inline unsigned int cvtpk_bf16(float a, float b) {
    unsigned int r;
    asm("v_cvt_pk_bf16_f32 %0, %1, %2" : "=v"(r) : "v"(a), "v"(b));
    return r;  // lo = bf16(a), hi = bf16(b)
}

// softmax scale with log2(e) folded in: exp2(q*k*QSCALE) == exp(q*k/sqrt(32))
#define QSCALE (0.17677669529663689f * 1.4426950408889634f)

// ---------------------------------------------------------------------------
// Split-bf16 MFMA GEMM with split-K, double-buffered LDS + reg prefetch.
// C[i,j] = sum_k A[i,k]*B[j,k] (+bias[j] if gridDim.z==1 && bias)
// r19: hi/lo split via v_cvt_pk_bf16_f32 (1 pk for hi pair, exact residual
// by Sterbenz, 1 pk for lo pair) — ~4x fewer VALU ops than scalar f2bf,
// BIT-IDENTICAL plane values (same RNE rounding).
// Epilogue modes:
//   qb_out != null : write f2bf(val*QSCALE) to qb_out[row*N+col]; skip C.
//   kb_out != null : write C as usual; ALSO if col<128 write tiled bf16 K:
//                    kb_out[((h*KTp+kt)*128+mi)*32+c].
// ---------------------------------------------------------------------------
__global__ __launch_bounds__(256) void gemm_split_kernel(
    const float* __restrict__ A, const float* __restrict__ B,
    const float* __restrict__ bias, float* __restrict__ C,
    int M, int N, int K,
    unsigned short* __restrict__ qb_out,
    unsigned short* __restrict__ kb_out, int KTp) {
    __shared__ unsigned short Ah[2][2560], Al[2][2560], Bh[2][2560], Bl[2][2560];
    int t = threadIdx.x;
    int wave = t >> 6, lane = t & 63;
    int lg = lane >> 4, lc = lane & 15;
    int wm = wave >> 1, wn = wave & 1;
    int m0 = blockIdx.y * 64, n0 = blockIdx.x * 64;
    int Kc = K / gridDim.z;
    int kbeg = blockIdx.z * Kc;
    float* Cz = C + (long)blockIdx.z * M * N;
    int srow = t >> 2, sc8 = (t & 3) * 8;
    const float* aBase = A + (long)(m0 + srow) * K + kbeg + sc8;
    const float* bBase = B + (long)(n0 + srow) * K + kbeg + sc8;
    int nIter = Kc / 32;

    f32x4 acc[2][2];
#pragma unroll
    for (int i = 0; i < 2; ++i)
#pragma unroll
        for (int j = 0; j < 2; ++j) acc[i][j] = (f32x4){0.f, 0.f, 0.f, 0.f};

    // split 8 f32 into hi/lo bf16 planes via cvt_pk; residual exact (Sterbenz)
    auto split8 = [](f32x4 v0, f32x4 v1, u32x4& hw, u32x4& lw) {
        float av[8] = {v0[0], v0[1], v0[2], v0[3], v1[0], v1[1], v1[2], v1[3]};
#pragma unroll
        for (int p = 0; p < 4; ++p) {
            float x0 = av[2 * p], x1 = av[2 * p + 1];
            unsigned int w = cvtpk_bf16(x0, x1);
            float h0 = __builtin_bit_cast(float, w << 16);
            float h1 = __builtin_bit_cast(float, w & 0xFFFF0000u);
            hw[p] = w;
            lw[p] = cvtpk_bf16(x0 - h0, x1 - h1);
        }
    };
    auto cvt_store = [&](int buf, f32x4 a0, f32x4 a1, f32x4 b0, f32x4 b1) {
        u32x4 hw, lw;
        split8(a0, a1, hw, lw);
        *reinterpret_cast<u32x4*>(&Ah[buf][srow * 40 + sc8]) = hw;
        *reinterpret_cast<u32x4*>(&Al[buf][srow * 40 + sc8]) = lw;
        split8(b0, b1, hw, lw);
        *reinterpret_cast<u32x4*>(&Bh[buf][srow * 40 + sc8]) = hw;
        *reinterpret_cast<u32x4*>(&Bl[buf][srow * 40 + sc8]) = lw;
    };

    {
        f32x4 a0 = *reinterpret_cast<const f32x4*>(aBase);
        f32x4 a1 = *reinterpret_cast<const f32x4*>(aBase + 4);
        f32x4 b0 = *reinterpret_cast<const f32x4*>(bBase);
        f32x4 b1 = *reinterpret_cast<const f32x4*>(bBase + 4);
        cvt_store(0, a0, a1, b0, b1);
    }
    __syncthreads();

    for (int k = 0; k < nIter; ++k) {
        int cur = k & 1;
        bool more = (k + 1 < nIter);
        f32x4 na0, na1, nb0, nb1;
        if (more) {
            const float* ap = aBase + (k + 1) * 32;
            const float* bp = bBase + (k + 1) * 32;
            na0 = *reinterpret_cast<const f32x4*>(ap);
            na1 = *reinterpret_cast<const f32x4*>(ap + 4);
            nb0 = *reinterpret_cast<const f32x4*>(bp);
            nb1 = *reinterpret_cast<const f32x4*>(bp + 4);
        }
        bf16x8 afh[2], afl[2], bfh[2], bfl[2];
#pragma unroll
        for (int i = 0; i < 2; ++i) {
            int ar = wm * 32 + i * 16 + lc;
            afh[i] = *reinterpret_cast<const bf16x8*>(&Ah[cur][ar * 40 + lg * 8]);
            afl[i] = *reinterpret_cast<const bf16x8*>(&Al[cur][ar * 40 + lg * 8]);
            int br = wn * 32 + i * 16 + lc;
            bfh[i] = *reinterpret_cast<const bf16x8*>(&Bh[cur][br * 40 + lg * 8]);
            bfl[i] = *reinterpret_cast<const bf16x8*>(&Bl[cur][br * 40 + lg * 8]);
        }
#pragma unroll
        for (int i = 0; i < 2; ++i)
#pragma unroll
            for (int j = 0; j < 2; ++j) {
                acc[i][j] = __builtin_amdgcn_mfma_f32_16x16x32_bf16(afh[i], bfh[j], acc[i][j], 0, 0, 0);
                acc[i][j] = __builtin_amdgcn_mfma_f32_16x16x32_bf16(afh[i], bfl[j], acc[i][j], 0, 0, 0);
                acc[i][j] = __builtin_amdgcn_mfma_f32_16x16x32_bf16(afl[i], bfh[j], acc[i][j], 0, 0, 0);
            }
        if (more) {
            cvt_store(cur ^ 1, na0, na1, nb0, nb1);
            __syncthreads();
        }
    }
#pragma unroll
    for (int i = 0; i < 2; ++i)
#pragma unroll
        for (int j = 0; j < 2; ++j)
#pragma unroll
            for (int r = 0; r < 4; ++r) {
                int row = m0 + wm * 32 + i * 16 + lg * 4 + r;
                int col = n0 + wn * 32 + j * 16 + lc;
                float bv = bias ? bias[col] : 0.f;
                float val = acc[i][j][r] + bv;
                if (qb_out) {
                    qb_out[(long)row * N + col] = f2bf(val * QSCALE);
                } else {
                    Cz[(long)row * N + col] = val;
                    if (kb_out && col < 128) {
                        int h = col >> 5, c = col & 31, kt = row >> 7, mi = row & 127;
                        kb_out[((long)(h * KTp + kt) * 128 + mi) * 32 + c] = f2bf(val);
                    }
                }
            }
}

// ---------------------------------------------------------------------------
// Fused: sum KS split-K planes + bias, then LayerNorm + exact GELU.
// ---------------------------------------------------------------------------
__global__ void reduce_ln_gelu_kernel(const float* __restrict__ part,
                                      const float* __restrict__ bias,
                                      const float* __restrict__ g,
                                      const float* __restrict__ bb,
                                      float* __restrict__ xr, int MN, int KS) {
    int m = blockIdx.x;
    int c = threadIdx.x;
    float v = bias[c];
    for (int z = 0; z < KS; ++z) v += part[(long)z * MN + m * C_DIM + c];
    __shared__ float wred[4];
    float s = v;
    for (int off = 32; off; off >>= 1) s += __shfl_down(s, off);
    if ((c & 63) == 0) wred[c >> 6] = s;
    __syncthreads();
    float mean = (wred[0] + wred[1] + wred[2] + wred[3]) * (1.f / 256.f);
    __syncthreads();
    float d = v - mean;
    float s2 = d * d;
    for (int off = 32; off; off >>= 1) s2 += __shfl_down(s2, off);
    if ((c & 63) == 0) wred[c >> 6] = s2;
    __syncthreads();
    float var = (wred[0] + wred[1] + wred[2] + wred[3]) * (1.f / 256.f);
    float y = d * rsqrtf(var + 1e-5f) * g[c] + bb[c];
    float ge = 0.5f * y * (1.f + erff(y * 0.70710678118654752f));
    xr[m * C_DIM + c] = ge;
}

// ---------------------------------------------------------------------------
// im2col for SR conv.
// ---------------------------------------------------------------------------
template <int S>
__global__ void im2col_kernel(const float* __restrict__ x, float* __restrict__ im, int Ws) {
    constexpr int T = S * S;
    __shared__ float patch[T * 257];
    int m = blockIdx.x;
    int z = m % ZZ;
    int wo = (m / ZZ) % Ws;
    int ho = m / (ZZ * Ws);
    int t = threadIdx.x;
#pragma unroll
    for (int tap = 0; tap < T; ++tap) {
        int kh = tap / S, kw = tap % S;
        int row = (ho * S + kh) * (WW * ZZ) + (wo * S + kw) * ZZ + z;
        patch[tap * 257 + t] = x[row * C_DIM + t];
    }
    __syncthreads();
#pragma unroll
    for (int rep = 0; rep < T; ++rep) {
        int k = rep * 256 + t;
        int ci = k / T, tap = k % T;
        im[(long)m * (256 * T) + k] = patch[tap * 257 + ci];
    }
}

// ---------------------------------------------------------------------------
// LayerNorm + exact GELU (fallback path when split-K not used)
// ---------------------------------------------------------------------------
__global__ void ln_gelu_kernel(float* __restrict__ xr, const float* __restrict__ g,
                               const float* __restrict__ bb) {
    int m = blockIdx.x;
    int c = threadIdx.x;
    float v = xr[m * C_DIM + c];
    __shared__ float wred[4];
    float s = v;
    for (int off = 32; off; off >>= 1) s += __shfl_down(s, off);
    if ((c & 63) == 0) wred[c >> 6] = s;
    __syncthreads();
    float mean = (wred[0] + wred[1] + wred[2] + wred[3]) * (1.f / 256.f);
    __syncthreads();
    float d = v - mean;
    float s2 = d * d;
    for (int off = 32; off; off >>= 1) s2 += __shfl_down(s2, off);
    if ((c & 63) == 0) wred[c >> 6] = s2;
    __syncthreads();
    float var = (wred[0] + wred[1] + wred[2] + wred[3]) * (1.f / 256.f);
    float y = d * rsqrtf(var + 1e-5f) * g[c] + bb[c];
    float ge = 0.5f * y * (1.f + erff(y * 0.70710678118654752f));
    xr[m * C_DIM + c] = ge;
}

// ---------------------------------------------------------------------------
// Depthwise 3x3x1 conv on V + residual; writes tiled V^T bf16:
// vt[((hh*KT+kt)*32 + d)*128 + s], where slot s holds key mi per the
// in-register P order of the swapped-QK attention:
//   mi = a<<5 | u<<4 | g<<2 | v  ->  s = a<<5 | g<<3 | u<<2 | v
// (a=mi>>5 2b, u=(mi>>4)&1, g=(mi>>2)&3, v=mi&3; bijective).
// ---------------------------------------------------------------------------
__global__ void dw_conv_kernel(const float* __restrict__ kv, const float* __restrict__ lw,
                               const float* __restrict__ lb, unsigned short* __restrict__ vt,
                               int Ws, int Hs, int KT) {
    int m = blockIdx.x;
    int ch = threadIdx.x;
    int z = m % ZZ;
    int wo = (m / ZZ) % Ws;
    int ho = m / (ZZ * Ws);
    float acc = lb[ch];
#pragma unroll
    for (int kh = 0; kh < 3; ++kh) {
        int h = ho + kh - 1;
        if (h < 0 || h >= Hs) continue;
#pragma unroll
        for (int kw = 0; kw < 3; ++kw) {
            int w2 = wo + kw - 1;
            if (w2 < 0 || w2 >= Ws) continue;
            int mm = (h * Ws + w2) * ZZ + z;
            acc += kv[mm * C_DIM + 128 + ch] * lw[ch * 9 + kh * 3 + kw];
        }
    }
    int hh = ch >> 5, d = ch & 31, kt = m >> 7, mi = m & 127;
    int a = mi >> 5, u = (mi >> 4) & 1, g = (mi >> 2) & 3, v = mi & 3;
    int s = (a << 5) | (g << 3) | (u << 2) | v;
    vt[((long)(hh * KT + kt) * 32 + d) * 128 + s] = f2bf(kv[m * C_DIM + 128 + ch] + acc);
}

// ---------------------------------------------------------------------------
// Fused MFMA flash attention, both branches, NO-MAX softmax, SWAPPED-QK,
// FULLY IN-REGISTER SOFTMAX (zero LDS), TWO Q-GROUPS PER WAVE,
// double-buffered K and V prefetch (passing r18 structure, unchanged).
// Grid (64, 8), 256 threads = 4 waves; wave w owns 32 q-rows as two 16-row
// groups qf0/qf1 SHARING the K/V fragment loads.
// kb tiled: [h][kt][128 keys][32 d]; vt slot-permuted [h][kt][32 d][128 pos].
// ---------------------------------------------------------------------------
__global__ __launch_bounds__(256, 2) void attn_fused_kernel(
    const unsigned short* __restrict__ qb,
    const unsigned short* __restrict__ kb1, const unsigned short* __restrict__ vt1,
    const unsigned short* __restrict__ kb2, const unsigned short* __restrict__ vt2,
    float* __restrict__ outcat) {
    int wave = threadIdx.x >> 6;
    int lane = threadIdx.x & 63;
    int lg = lane >> 4;
    int lc = lane & 15;
    int by = blockIdx.y;
    int big = ((by >> 2) == 0);  // by 0..3 = branch-2 (M=2048), dispatched first
    int head = by & 3;
    const unsigned short* kb = big ? kb2 : kb1;
    const unsigned short* vt = big ? vt2 : vt1;
    int KT = big ? 16 : 4;
    int col_base = big ? 128 : 0;
    int q0 = blockIdx.x * 128 + wave * 32;

    bf16x8 qf0 = *reinterpret_cast<const bf16x8*>(qb + (long)(q0 + lc) * C_DIM + col_base + head * HD + lg * 8);
    bf16x8 qf1 = *reinterpret_cast<const bf16x8*>(qb + (long)(q0 + 16 + lc) * C_DIM + col_base + head * HD + lg * 8);

    const unsigned short* kbase = kb + (long)head * KT * 4096;
    const unsigned short* vbase = vt + (long)head * KT * 4096;

    f32x4 o00 = {0.f, 0.f, 0.f, 0.f}, o01 = {0.f, 0.f, 0.f, 0.f};
    f32x4 o10 = {0.f, 0.f, 0.f, 0.f}, o11 = {0.f, 0.f, 0.f, 0.f};
    float lsum0 = 0.f, lsum1 = 0.f;

    bf16x8 kf[8];
    bf16x8 vf0c[4], vf1c[4];
#pragma unroll
    for (int c = 0; c < 8; ++c)
        kf[c] = *reinterpret_cast<const bf16x8*>(kbase + (16 * c + lc) * 32 + lg * 8);
#pragma unroll
    for (int c2 = 0; c2 < 4; ++c2) {
        vf0c[c2] = *reinterpret_cast<const bf16x8*>(vbase + lc * 128 + c2 * 32 + lg * 8);
        vf1c[c2] = *reinterpret_cast<const bf16x8*>(vbase + (16 + lc) * 128 + c2 * 32 + lg * 8);
    }

    for (int kt = 0; kt < KT; ++kt) {
        // QK^T swapped, both q-groups share kf: s*[c][r] = S[key=16c+4lg+r][query=lc]
        f32x4 s0[8], s1[8];
        f32x4 z = {0.f, 0.f, 0.f, 0.f};
#pragma unroll
        for (int c = 0; c < 8; ++c) {
            s0[c] = __builtin_amdgcn_mfma_f32_16x16x32_bf16(kf[c], qf0, z, 0, 0, 0);
            s1[c] = __builtin_amdgcn_mfma_f32_16x16x32_bf16(kf[c], qf1, z, 0, 0, 0);
        }
        // prefetch next tile's K (overwrite, consumed) AND V (separate bufs)
        bf16x8 vf0n[4], vf1n[4];
        if (kt + 1 < KT) {
            const unsigned short* knext = kbase + (long)(kt + 1) * 4096;
            const unsigned short* vnext = vbase + (long)(kt + 1) * 4096;
#pragma unroll
            for (int c = 0; c < 8; ++c)
                kf[c] = *reinterpret_cast<const bf16x8*>(knext + (16 * c + lc) * 32 + lg * 8);
#pragma unroll
            for (int c2 = 0; c2 < 4; ++c2) {
                vf0n[c2] = *reinterpret_cast<const bf16x8*>(vnext + lc * 128 + c2 * 32 + lg * 8);
                vf1n[c2] = *reinterpret_cast<const bf16x8*>(vnext + (16 + lc) * 128 + c2 * 32 + lg * 8);
            }
        }
        // in-register softmax + PV A-frag packing, group 0 then group 1
#pragma unroll
        for (int c2 = 0; c2 < 4; ++c2) {
            unsigned int w0, w1, w2, w3;
            {
                int c = 2 * c2;
                float p0 = __builtin_amdgcn_exp2f(s0[c][0]);
                float p1 = __builtin_amdgcn_exp2f(s0[c][1]);
                float p2 = __builtin_amdgcn_exp2f(s0[c][2]);
                float p3 = __builtin_amdgcn_exp2f(s0[c][3]);
                lsum0 += (p0 + p1) + (p2 + p3);
                w0 = cvtpk_bf16(p0, p1);
                w1 = cvtpk_bf16(p2, p3);
            }
            {
                int c = 2 * c2 + 1;
                float p0 = __builtin_amdgcn_exp2f(s0[c][0]);
                float p1 = __builtin_amdgcn_exp2f(s0[c][1]);
                float p2 = __builtin_amdgcn_exp2f(s0[c][2]);
                float p3 = __builtin_amdgcn_exp2f(s0[c][3]);
                lsum0 += (p0 + p1) + (p2 + p3);
                w2 = cvtpk_bf16(p0, p1);
                w3 = cvtpk_bf16(p2, p3);
            }
            u32x4 pw = {w0, w1, w2, w3};
            bf16x8 pa = __builtin_bit_cast(bf16x8, pw);
            o00 = __builtin_amdgcn_mfma_f32_16x16x32_bf16(pa, vf0c[c2], o00, 0, 0, 0);
            o01 = __builtin_amdgcn_mfma_f32_16x16x32_bf16(pa, vf1c[c2], o01, 0, 0, 0);
        }
#pragma unroll
        for (int c2 = 0; c2 < 4; ++c2) {
            unsigned int w0, w1, w2, w3;
            {
                int c = 2 * c2;
                float p0 = __builtin_amdgcn_exp2f(s1[c][0]);
                float p1 = __builtin_amdgcn_exp2f(s1[c][1]);
                float p2 = __builtin_amdgcn_exp2f(s1[c][2]);
                float p3 = __builtin_amdgcn_exp2f(s1[c][3]);
                lsum1 += (p0 + p1) + (p2 + p3);
                w0 = cvtpk_bf16(p0, p1);
                w1 = cvtpk_bf16(p2, p3);
            }
            {
                int c = 2 * c2 + 1;
                float p0 = __builtin_amdgcn_exp2f(s1[c][0]);
                float p1 = __builtin_amdgcn_exp2f(s1[c][1]);
                float p2 = __builtin_amdgcn_exp2f(s1[c][2]);
                float p3 = __builtin_amdgcn_exp2f(s1[c][3]);
                lsum1 += (p0 + p1) + (p2 + p3);
                w2 = cvtpk_bf16(p0, p1);
                w3 = cvtpk_bf16(p2, p3);
            }
            u32x4 pw = {w0, w1, w2, w3};
            bf16x8 pa = __builtin_bit_cast(bf16x8, pw);
            o10 = __builtin_amdgcn_mfma_f32_16x16x32_bf16(pa, vf0c[c2], o10, 0, 0, 0);
            o11 = __builtin_amdgcn_mfma_f32_16x16x32_bf16(pa, vf1c[c2], o11, 0, 0, 0);
        }
        if (kt + 1 < KT) {
#pragma unroll
            for (int c2 = 0; c2 < 4; ++c2) {
                vf0c[c2] = vf0n[c2];
                vf1c[c2] = vf1n[c2];
            }
        }
    }
    // reduce each group's lsum across the 4 lg-groups, then distribute
    lsum0 += __shfl_xor(lsum0, 16);
    lsum0 += __shfl_xor(lsum0, 32);
    lsum1 += __shfl_xor(lsum1, 16);
    lsum1 += __shfl_xor(lsum1, 32);
#pragma unroll
    for (int r = 0; r < 4; ++r) {
        float ls = __shfl(lsum0, lg * 4 + r);
        float inv = 1.f / ls;
        int row = q0 + lg * 4 + r;
        outcat[(long)row * C_DIM + col_base + head * HD + lc] = o00[r] * inv;
        outcat[(long)row * C_DIM + col_base + head * HD + 16 + lc] = o01[r] * inv;
    }
#pragma unroll
    for (int r = 0; r < 4; ++r) {
        float ls = __shfl(lsum1, lg * 4 + r);
        float inv = 1.f / ls;
        int row = q0 + 16 + lg * 4 + r;
        outcat[(long)row * C_DIM + col_base + head * HD + lc] = o10[r] * inv;
        outcat[(long)row * C_DIM + col_base + head * HD + 16 + lc] = o11[r] * inv;
    }
}

// ---------------------------------------------------------------------------
extern "C" void kernel_launch(void* const* d_in, const int* in_sizes, int n_in,
                              void* d_out, int out_size, void* d_ws, size_t ws_size,
                              hipStream_t stream) {
    const float* x      = (const float*)d_in[0];
    const float* Wq     = (const float*)d_in[1];
    const float* sr1_w  = (const float*)d_in[2];
    const float* sr1_b  = (const float*)d_in[3];
    const float* ln1_w  = (const float*)d_in[4];
    const float* ln1_b  = (const float*)d_in[5];
    const float* sr2_w  = (const float*)d_in[6];
    const float* sr2_b  = (const float*)d_in[7];
    const float* ln2_w  = (const float*)d_in[8];
    const float* ln2_b  = (const float*)d_in[9];
    const float* Wkv1   = (const float*)d_in[10];
    const float* Wkv2   = (const float*)d_in[11];
    const float* lc1_w  = (const float*)d_in[12];
    const float* lc1_b  = (const float*)d_in[13];
    const float* lc2_w  = (const float*)d_in[14];
    const float* lc2_b  = (const float*)d_in[15];
    const float* proj_w = (const float*)d_in[16];
    const float* proj_b = (const float*)d_in[17];
    float* out = (float*)d_out;
    char* wsb = (char*)d_ws;

    float* buf0 = (float*)wsb;                                  // sr1 partials -> cat (8 MB)
    unsigned short* qb = (unsigned short*)(wsb + 8388608);      // 4 MB
    float* im = (float*)(wsb + 12582912);                       // 8 MB
    float* xr1 = (float*)(wsb + 20971520);
    float* kv1 = (float*)(wsb + 21495808);
    unsigned short* kb1 = (unsigned short*)(wsb + 22020096);
    unsigned short* vt1 = (unsigned short*)(wsb + 22151168);
    float* xr2 = (float*)(wsb + 22282240);
    float* kv2 = (float*)(wsb + 24379392);
    unsigned short* kb2 = (unsigned short*)(wsb + 26476544);
    unsigned short* vt2 = (unsigned short*)(wsb + 27000832);
    float* part2 = (float*)(wsb + 27525120);

    float* cat = buf0;
    float* part1 = buf0;

    int KS2 = 1;
    if (ws_size >= 27525120ull + 4ull * 2048 * 256 * 4) KS2 = 4;
    else if (ws_size >= 27525120ull + 2ull * 2048 * 256 * 4) KS2 = 2;

    // q = bf16(scale * x @ Wq.T), fused epilogue
    gemm_split_kernel<<<dim3(4, 128, 1), 256, 0, stream>>>(x, Wq, nullptr, (float*)qb, 8192, 256, 256,
                                                           qb, nullptr, 0);

    // ---- branch 1 (stride 4): M = 512, K = 4096, split-K 16 ----
    im2col_kernel<4><<<512, 256, 0, stream>>>(x, im, 8);
    gemm_split_kernel<<<dim3(4, 8, 16), 256, 0, stream>>>(im, sr1_w, nullptr, part1, 512, 256, 4096,
                                                          nullptr, nullptr, 0);
    reduce_ln_gelu_kernel<<<512, 256, 0, stream>>>(part1, sr1_b, ln1_w, ln1_b, xr1, 512 * 256, 16);
    gemm_split_kernel<<<dim3(4, 8, 1), 256, 0, stream>>>(xr1, Wkv1, nullptr, kv1, 512, 256, 256,
                                                         nullptr, kb1, 4);
    dw_conv_kernel<<<512, 128, 0, stream>>>(kv1, lc1_w, lc1_b, vt1, 8, 8, 4);

    // ---- branch 2 (stride 2): M = 2048, K = 1024, split-K KS2 ----
    im2col_kernel<2><<<2048, 256, 0, stream>>>(x, im, 16);
    if (KS2 > 1) {
        gemm_split_kernel<<<dim3(4, 32, KS2), 256, 0, stream>>>(im, sr2_w, nullptr, part2, 2048, 256, 1024,
                                                                nullptr, nullptr, 0);
        reduce_ln_gelu_kernel<<<2048, 256, 0, stream>>>(part2, sr2_b, ln2_w, ln2_b, xr2, 2048 * 256, KS2);
    } else {
        gemm_split_kernel<<<dim3(4, 32, 1), 256, 0, stream>>>(im, sr2_w, sr2_b, xr2, 2048, 256, 1024,
                                                              nullptr, nullptr, 0);
        ln_gelu_kernel<<<2048, 256, 0, stream>>>(xr2, ln2_w, ln2_b);
    }
    gemm_split_kernel<<<dim3(4, 32, 1), 256, 0, stream>>>(xr2, Wkv2, nullptr, kv2, 2048, 256, 256,
                                                          nullptr, kb2, 16);
    dw_conv_kernel<<<2048, 128, 0, stream>>>(kv2, lc2_w, lc2_b, vt2, 16, 16, 16);

    // fused attention over both branches (4 waves / 128 q-rows per block)
    attn_fused_kernel<<<dim3(64, 8), 256, 0, stream>>>(qb, kb1, vt1, kb2, vt2, cat);

    // out = cat @ proj_w.T + proj_b
    gemm_split_kernel<<<dim3(4, 128, 1), 256, 0, stream>>>(cat, proj_w, proj_b, out, 8192, 256, 256,
                                                           nullptr, nullptr, 0);
}